// Round 5
// baseline (41.169 us; speedup 1.0000x reference)
//
#include <hip/hip_runtime.h>
#include <stdint.h>

typedef float    f32x4 __attribute__((ext_vector_type(4)));
typedef uint32_t u32x4 __attribute__((ext_vector_type(4)));

// LDS layout (bytes):
//  [0, 65536)       fp8 codebook, t-grouped lane order:
//                   tile t, lane l=(lg*16+lr): 16B at t*1024 + l*16 =
//                   { fp8(1024*e[16t+lr][lg*8 .. +8)), fp8(1024*e[16t+lr][32+lg*8 .. +8)) }
//  [65536, 69632)   e2 fp32[1024] (unscaled, exact)
//  [69632, 70656)   idx exchange: 8 waves * 32 int
//  [70656, 70688)   loss scratch: 8 floats
#define SM_E2   65536
#define SM_IDX  69632
#define SM_LOSS 70656
#define SM_SZ   70688

__device__ __forceinline__ uint32_t pk4(float a, float b, float c, float d) {
  int v = 0;
  v = __builtin_amdgcn_cvt_pk_fp8_f32(a, b, v, false);
  v = __builtin_amdgcn_cvt_pk_fp8_f32(c, d, v, true);
  return (uint32_t)v;
}

__device__ __forceinline__ float d4(f32x4 v) {
  return v[0]*v[0] + v[1]*v[1] + v[2]*v[2] + v[3]*v[3];
}

// fused: conversion + argmax-scan + gather/store + loss, one kernel
__global__ __launch_bounds__(512, 4) void vq_fused(const float* __restrict__ x,
                                                   const float* __restrict__ cb,
                                                   float* __restrict__ out,
                                                   float* __restrict__ loss) {
  __shared__ __align__(16) uint8_t smem[SM_SZ];
  const int tid = threadIdx.x, lane = tid & 63, w = tid >> 6;
  const int lr = lane & 15, lg = lane >> 4;
  const int rowbase = blockIdx.x * 256 + w * 32;

  // ---- 1. issue x loads first (nontemporal; stream under conversion) ----
  f32x4 r0[2][4];
#pragma unroll
  for (int rt = 0; rt < 2; ++rt) {
    const float* rp = x + (size_t)(rowbase + rt * 16 + lr) * 64 + lg * 8;
    r0[rt][0] = __builtin_nontemporal_load((const f32x4*)rp);
    r0[rt][1] = __builtin_nontemporal_load((const f32x4*)(rp + 4));
    r0[rt][2] = __builtin_nontemporal_load((const f32x4*)(rp + 32));
    r0[rt][3] = __builtin_nontemporal_load((const f32x4*)(rp + 36));
  }

  // ---- 2. in-block codebook conversion: rows tid, tid+512 (L2-served) ----
#pragma unroll
  for (int h = 0; h < 2; ++h) {
    const int j = tid + h * 512;
    const float* rp = cb + (size_t)j * 64;
    const int t = j >> 4, jr = j & 15;
    float e2 = 0.f;
#pragma unroll
    for (int g = 0; g < 4; ++g) {
      f32x4 a0 = *(const f32x4*)(rp + g * 8);
      f32x4 a1 = *(const f32x4*)(rp + g * 8 + 4);
      f32x4 b0 = *(const f32x4*)(rp + 32 + g * 8);
      f32x4 b1 = *(const f32x4*)(rp + 32 + g * 8 + 4);
      e2 += d4(a0) + d4(a1) + d4(b0) + d4(b1);
      u32x4 o;
      o[0] = pk4(1024.f*a0[0], 1024.f*a0[1], 1024.f*a0[2], 1024.f*a0[3]);
      o[1] = pk4(1024.f*a1[0], 1024.f*a1[1], 1024.f*a1[2], 1024.f*a1[3]);
      o[2] = pk4(1024.f*b0[0], 1024.f*b0[1], 1024.f*b0[2], 1024.f*b0[3]);
      o[3] = pk4(1024.f*b1[0], 1024.f*b1[1], 1024.f*b1[2], 1024.f*b1[3]);
      *(u32x4*)(smem + t * 1024 + g * 256 + jr * 16) = o;
    }
    ((float*)(smem + SM_E2))[j] = e2;
  }

  // ---- 3. pack A fragments + x^2 partial (x loads have landed by now) ----
  float x2p = 0.f;
  long afrag[2][2];
#pragma unroll
  for (int rt = 0; rt < 2; ++rt) {
    x2p += d4(r0[rt][0]) + d4(r0[rt][1]) + d4(r0[rt][2]) + d4(r0[rt][3]);
    uint32_t w0 = pk4(r0[rt][0][0], r0[rt][0][1], r0[rt][0][2], r0[rt][0][3]);
    uint32_t w1 = pk4(r0[rt][1][0], r0[rt][1][1], r0[rt][1][2], r0[rt][1][3]);
    uint32_t w2 = pk4(r0[rt][2][0], r0[rt][2][1], r0[rt][2][2], r0[rt][2][3]);
    uint32_t w3 = pk4(r0[rt][3][0], r0[rt][3][1], r0[rt][3][2], r0[rt][3][3]);
    afrag[rt][0] = (long)(((uint64_t)w1 << 32) | w0);
    afrag[rt][1] = (long)(((uint64_t)w3 << 32) | w2);
  }
  __syncthreads();   // codebook LDS ready

  // ---- 4. scan all 64 code-tiles, paired (invites v_max3 fusion) ----
  float kmax[2][4];
#pragma unroll
  for (int rt = 0; rt < 2; ++rt)
#pragma unroll
    for (int r = 0; r < 4; ++r) kmax[rt][r] = __builtin_bit_cast(float, 0xFF800000u);

  const uint8_t* bptr = smem + lane * 16;
  uint32_t jv = (uint32_t)lr;
#pragma unroll 4
  for (int tp = 0; tp < 32; ++tp) {
    u32x4 bA = *(const u32x4*)(bptr + (tp * 2) * 1024);
    u32x4 bB = *(const u32x4*)(bptr + (tp * 2 + 1) * 1024);
    long bA0 = (long)(((uint64_t)bA[1] << 32) | bA[0]);
    long bA1 = (long)(((uint64_t)bA[3] << 32) | bA[2]);
    long bB0 = (long)(((uint64_t)bB[1] << 32) | bB[0]);
    long bB1 = (long)(((uint64_t)bB[3] << 32) | bB[2]);
    uint32_t jvB = jv | 16u;
#pragma unroll
    for (int rt = 0; rt < 2; ++rt) {
      f32x4 accA = {0.f, 0.f, 0.f, 0.f}, accB = {0.f, 0.f, 0.f, 0.f};
      accA = __builtin_amdgcn_mfma_f32_16x16x32_fp8_fp8(afrag[rt][0], bA0, accA, 0, 0, 0);
      accA = __builtin_amdgcn_mfma_f32_16x16x32_fp8_fp8(afrag[rt][1], bA1, accA, 0, 0, 0);
      accB = __builtin_amdgcn_mfma_f32_16x16x32_fp8_fp8(afrag[rt][0], bB0, accB, 0, 0, 0);
      accB = __builtin_amdgcn_mfma_f32_16x16x32_fp8_fp8(afrag[rt][1], bB1, accB, 0, 0, 0);
#pragma unroll
      for (int r = 0; r < 4; ++r) {
        uint32_t kA = (__builtin_bit_cast(uint32_t, accA[r]) & 0xFFFFFC00u) | jv;
        uint32_t kB = (__builtin_bit_cast(uint32_t, accB[r]) & 0xFFFFFC00u) | jvB;
        kmax[rt][r] = fmaxf(fmaxf(kmax[rt][r], __builtin_bit_cast(float, kA)),
                            __builtin_bit_cast(float, kB));
      }
    }
    jv += 32;
  }

  // ---- 5. reduce over 16 code-slot lanes; loss dot term ----
  float lsum = x2p;
#pragma unroll
  for (int rt = 0; rt < 2; ++rt)
#pragma unroll
    for (int r = 0; r < 4; ++r) {
      float v = kmax[rt][r];
#pragma unroll
      for (int m = 1; m < 16; m <<= 1) v = fmaxf(v, __shfl_xor(v, m, 64));
      kmax[rt][r] = v;
      // acc = 1024*(x.e); -2*dot per row, replicated over 16 lanes -> /8192
      lsum -= __builtin_bit_cast(float, __builtin_bit_cast(uint32_t, v) & 0xFFFFFC00u)
              * (1.0f / 8192.0f);
    }

  // ---- 6. idx exchange (wave-local) ----
  int* sh_idx = (int*)(smem + SM_IDX) + w * 32;
  if (lr == 0) {
#pragma unroll
    for (int rt = 0; rt < 2; ++rt)
#pragma unroll
      for (int r = 0; r < 4; ++r)
        sh_idx[rt * 16 + lg * 4 + r] =
            (int)(__builtin_bit_cast(uint32_t, kmax[rt][r]) & 1023u);
  }
  asm volatile("s_waitcnt lgkmcnt(0)" ::: "memory");

  // ---- 7. gather fp32 codebook rows (L2) + store + e2 loss term ----
  const float* e2f = (const float*)(smem + SM_E2);
#pragma unroll
  for (int it = 0; it < 8; ++it) {
    int rloc = it * 4 + lg;
    int idx = sh_idx[rloc];
    f32x4 q = *(const f32x4*)(cb + (size_t)idx * 64 + lr * 4);
    __builtin_nontemporal_store(q, (f32x4*)(out + (size_t)(rowbase + rloc) * 64 + lr * 4));
    if (lr == 0) lsum += e2f[idx];
  }

  // ---- 8. loss: wave -> block -> global atomic ----
#pragma unroll
  for (int m = 1; m < 64; m <<= 1) lsum += __shfl_xor(lsum, m, 64);
  float* shl = (float*)(smem + SM_LOSS);
  if (lane == 0) shl[w] = lsum;
  __syncthreads();
  if (tid == 0) {
    float s = 0.f;
#pragma unroll
    for (int i = 0; i < 8; ++i) s += shl[i];
    atomicAdd(loss, s * (1.25f / 8388608.0f));
  }
}

extern "C" void kernel_launch(void* const* d_in, const int* in_sizes, int n_in,
                              void* d_out, int out_size, void* d_ws, size_t ws_size,
                              hipStream_t stream) {
  const float* x  = (const float*)d_in[0];
  const float* cb = (const float*)d_in[1];
  float* out = (float*)d_out;
  float* loss = out + 8388608;

  hipMemsetAsync(loss, 0, 4, stream);
  hipLaunchKernelGGL(vq_fused, dim3(512), dim3(512), 0, stream, x, cb, out, loss);
}

// Round 6
// 29.742 us; speedup vs baseline: 1.3842x; 1.3842x over previous
//
#include <hip/hip_runtime.h>
#include <stdint.h>

typedef float    f32x4 __attribute__((ext_vector_type(4)));
typedef uint32_t u32x4 __attribute__((ext_vector_type(4)));

// ws layout (bytes):
//  [0, 65536)       fp8 codebook, t-grouped lane order:
//                   chunk c = t*64 + l (t=code tile, l=lane): 16B at c*16 =
//                   { fp8(1024*e[16t+(l&15)][(l>>4)*8 .. +8)),
//                     fp8(1024*e[16t+(l&15)][32+(l>>4)*8 .. +8)) }
//  [65536, 69632)   e2 fp32[1024] (unscaled, exact)
#define WS_E2   65536

// LDS: mirrors ws [0,69632) linearly, + idx + loss scratch
#define SM_E2   65536
#define SM_IDX  69632   // 8 waves * 32 int = 1024B
#define SM_LOSS 70656   // 8 floats
#define SM_SZ   70688

__device__ __forceinline__ uint32_t pk4(float a, float b, float c, float d) {
  int v = 0;
  v = __builtin_amdgcn_cvt_pk_fp8_f32(a, b, v, false);
  v = __builtin_amdgcn_cvt_pk_fp8_f32(c, d, v, true);
  return (uint32_t)v;
}

__device__ __forceinline__ float d4(f32x4 v) {
  return v[0]*v[0] + v[1]*v[1] + v[2]*v[2] + v[3]*v[3];
}

// 8 blocks x 512: thread -> one 16B fp8 chunk + one e2 quarter-row (coalesced).
// Also zeroes the loss slot (replaces a memset dispatch).
__global__ __launch_bounds__(512) void prep_kernel(const float* __restrict__ cb,
                                                   uint8_t* __restrict__ ws,
                                                   float* __restrict__ loss) {
  const int tid = threadIdx.x;
  if (blockIdx.x == 0 && tid == 0) *loss = 0.f;
  const int c = blockIdx.x * 512 + tid;          // 0..4095
  const int t = c >> 6, l = c & 63, lr = l & 15, lg = l >> 4;
  {
    const float* row = cb + (size_t)(t * 16 + lr) * 64 + lg * 8;
    f32x4 a0 = *(const f32x4*)row;
    f32x4 a1 = *(const f32x4*)(row + 4);
    f32x4 b0 = *(const f32x4*)(row + 32);
    f32x4 b1 = *(const f32x4*)(row + 36);
    u32x4 o;
    o[0] = pk4(1024.f*a0[0], 1024.f*a0[1], 1024.f*a0[2], 1024.f*a0[3]);
    o[1] = pk4(1024.f*a1[0], 1024.f*a1[1], 1024.f*a1[2], 1024.f*a1[3]);
    o[2] = pk4(1024.f*b0[0], 1024.f*b0[1], 1024.f*b0[2], 1024.f*b0[3]);
    o[3] = pk4(1024.f*b1[0], 1024.f*b1[1], 1024.f*b1[2], 1024.f*b1[3]);
    *(u32x4*)(ws + (size_t)c * 16) = o;
  }
  {
    const int r = blockIdx.x * 128 + (tid >> 2), q = tid & 3;
    const float* rp = cb + (size_t)r * 64 + q * 16;
    f32x4 v0 = *(const f32x4*)rp;
    f32x4 v1 = *(const f32x4*)(rp + 4);
    f32x4 v2 = *(const f32x4*)(rp + 8);
    f32x4 v3 = *(const f32x4*)(rp + 12);
    float s = d4(v0) + d4(v1) + d4(v2) + d4(v3);
    s += __shfl_xor(s, 1, 64);
    s += __shfl_xor(s, 2, 64);
    if (q == 0) *(float*)(ws + WS_E2 + (size_t)r * 4) = s;
  }
}

// R2 core: 512 blocks x 512 threads, 32 rows/wave, ONE scan/wave, 16 waves/CU.
__global__ __launch_bounds__(512, 4) void vq_main(const float* __restrict__ x,
                                                  const float* __restrict__ cb,
                                                  float* __restrict__ out,
                                                  const uint8_t* __restrict__ ws,
                                                  float* __restrict__ loss) {
  __shared__ __align__(16) uint8_t smem[SM_SZ];
  const int tid = threadIdx.x, lane = tid & 63, w = tid >> 6;
  const int lr = lane & 15, lg = lane >> 4;
  const int rowbase = blockIdx.x * 256 + w * 32;

  // ---- issue async staging first: fp8 codebook (64KB) + e2 (4KB) ----
  {
    const uint8_t* gsrc = ws + (size_t)w * 8192 + (size_t)lane * 16;
    uint8_t* ldst = smem + w * 8192;
#pragma unroll
    for (int i = 0; i < 8; ++i)
      __builtin_amdgcn_global_load_lds(
          (const __attribute__((address_space(1))) uint32_t*)(gsrc + i * 1024),
          (__attribute__((address_space(3))) uint32_t*)(ldst + i * 1024), 16, 0, 0);
    if (w < 4)
      __builtin_amdgcn_global_load_lds(
          (const __attribute__((address_space(1))) uint32_t*)(ws + WS_E2 + (size_t)w * 1024 + (size_t)lane * 16),
          (__attribute__((address_space(3))) uint32_t*)(smem + SM_E2 + w * 1024), 16, 0, 0);
  }

  // ---- load x rows (nontemporal), fp32 x^2 partial, pack fp8 A-frags ----
  float x2p = 0.f;
  long afrag[2][2];
#pragma unroll
  for (int rt = 0; rt < 2; ++rt) {
    const float* rp = x + (size_t)(rowbase + rt * 16 + lr) * 64 + lg * 8;
    f32x4 a0 = __builtin_nontemporal_load((const f32x4*)rp);
    f32x4 a1 = __builtin_nontemporal_load((const f32x4*)(rp + 4));
    f32x4 b0 = __builtin_nontemporal_load((const f32x4*)(rp + 32));
    f32x4 b1 = __builtin_nontemporal_load((const f32x4*)(rp + 36));
    x2p += d4(a0) + d4(a1) + d4(b0) + d4(b1);
    uint32_t w0 = pk4(a0[0], a0[1], a0[2], a0[3]);
    uint32_t w1 = pk4(a1[0], a1[1], a1[2], a1[3]);
    uint32_t w2 = pk4(b0[0], b0[1], b0[2], b0[3]);
    uint32_t w3 = pk4(b1[0], b1[1], b1[2], b1[3]);
    afrag[rt][0] = (long)(((uint64_t)w1 << 32) | w0);
    afrag[rt][1] = (long)(((uint64_t)w3 << 32) | w2);
  }
  __syncthreads();

  // ---- single scan: 32 tile-PAIRS, keys via max3 ----
  float kmax[2][4];
#pragma unroll
  for (int rt = 0; rt < 2; ++rt)
#pragma unroll
    for (int r = 0; r < 4; ++r) kmax[rt][r] = __builtin_bit_cast(float, 0xFF800000u);

  const uint8_t* bptr = smem + lane * 16;
  uint32_t jv = (uint32_t)lr;
#pragma unroll 2
  for (int tp = 0; tp < 32; ++tp) {
    u32x4 bA = *(const u32x4*)(bptr + (size_t)(2 * tp) * 1024);
    u32x4 bB = *(const u32x4*)(bptr + (size_t)(2 * tp + 1) * 1024);
    long bA0 = (long)(((uint64_t)bA[1] << 32) | bA[0]);
    long bA1 = (long)(((uint64_t)bA[3] << 32) | bA[2]);
    long bB0 = (long)(((uint64_t)bB[1] << 32) | bB[0]);
    long bB1 = (long)(((uint64_t)bB[3] << 32) | bB[2]);
    uint32_t jvB = jv | 16u;
#pragma unroll
    for (int rt = 0; rt < 2; ++rt) {
      f32x4 accA = {0.f, 0.f, 0.f, 0.f}, accB = {0.f, 0.f, 0.f, 0.f};
      accA = __builtin_amdgcn_mfma_f32_16x16x32_fp8_fp8(afrag[rt][0], bA0, accA, 0, 0, 0);
      accA = __builtin_amdgcn_mfma_f32_16x16x32_fp8_fp8(afrag[rt][1], bA1, accA, 0, 0, 0);
      accB = __builtin_amdgcn_mfma_f32_16x16x32_fp8_fp8(afrag[rt][0], bB0, accB, 0, 0, 0);
      accB = __builtin_amdgcn_mfma_f32_16x16x32_fp8_fp8(afrag[rt][1], bB1, accB, 0, 0, 0);
#pragma unroll
      for (int r = 0; r < 4; ++r) {
        uint32_t kA = (__builtin_bit_cast(uint32_t, accA[r]) & 0xFFFFFC00u) | jv;
        uint32_t kB = (__builtin_bit_cast(uint32_t, accB[r]) & 0xFFFFFC00u) | jvB;
        kmax[rt][r] = fmaxf(fmaxf(kmax[rt][r], __builtin_bit_cast(float, kA)),
                            __builtin_bit_cast(float, kB));
      }
    }
    jv += 32;
  }

  // ---- reduce over the 16 code-slot lanes; loss dot term ----
  float lsum = x2p;
#pragma unroll
  for (int rt = 0; rt < 2; ++rt)
#pragma unroll
    for (int r = 0; r < 4; ++r) {
      float v = kmax[rt][r];
#pragma unroll
      for (int m = 1; m < 16; m <<= 1) v = fmaxf(v, __shfl_xor(v, m, 64));
      kmax[rt][r] = v;
      // acc = 1024*(x.e); -2*dot per row, replicated over 16 lanes -> /8192
      lsum -= __builtin_bit_cast(float, __builtin_bit_cast(uint32_t, v) & 0xFFFFFC00u)
              * (1.0f / 8192.0f);
    }

  // ---- idx exchange (wave-local) ----
  int* sh_idx = (int*)(smem + SM_IDX) + w * 32;
  if (lr == 0) {
#pragma unroll
    for (int rt = 0; rt < 2; ++rt)
#pragma unroll
      for (int r = 0; r < 4; ++r)
        sh_idx[rt * 16 + lg * 4 + r] =
            (int)(__builtin_bit_cast(uint32_t, kmax[rt][r]) & 1023u);
  }
  asm volatile("s_waitcnt lgkmcnt(0)" ::: "memory");

  // ---- gather fp32 codebook rows (L2) + store + e2 loss term ----
  const float* e2f = (const float*)(smem + SM_E2);
#pragma unroll
  for (int it = 0; it < 8; ++it) {
    int rloc = it * 4 + lg;
    int idx = sh_idx[rloc];
    f32x4 q = *(const f32x4*)(cb + (size_t)idx * 64 + lr * 4);
    __builtin_nontemporal_store(q, (f32x4*)(out + (size_t)(rowbase + rloc) * 64 + lr * 4));
    if (lr == 0) lsum += e2f[idx];
  }

  // ---- loss: wave -> block -> global atomic (zeroed by prep) ----
#pragma unroll
  for (int m = 1; m < 64; m <<= 1) lsum += __shfl_xor(lsum, m, 64);
  float* shl = (float*)(smem + SM_LOSS);
  if (lane == 0) shl[w] = lsum;
  __syncthreads();
  if (tid == 0) {
    float s = 0.f;
#pragma unroll
    for (int i = 0; i < 8; ++i) s += shl[i];
    atomicAdd(loss, s * (1.25f / 8388608.0f));
  }
}

extern "C" void kernel_launch(void* const* d_in, const int* in_sizes, int n_in,
                              void* d_out, int out_size, void* d_ws, size_t ws_size,
                              hipStream_t stream) {
  const float* x  = (const float*)d_in[0];
  const float* cb = (const float*)d_in[1];
  float* out = (float*)d_out;
  uint8_t* ws = (uint8_t*)d_ws;
  float* loss = out + 8388608;

  hipLaunchKernelGGL(prep_kernel, dim3(8), dim3(512), 0, stream, cb, ws, loss);
  hipLaunchKernelGGL(vq_main, dim3(512), dim3(512), 0, stream, x, cb, out, ws, loss);
}

// Round 7
// 29.732 us; speedup vs baseline: 1.3847x; 1.0003x over previous
//
#include <hip/hip_runtime.h>
#include <stdint.h>

typedef float    f32x4 __attribute__((ext_vector_type(4)));
typedef uint32_t u32x4 __attribute__((ext_vector_type(4)));

// ws layout (bytes):
//  [0, 65536)       fp8 codebook, t-grouped lane order:
//                   chunk c = t*64 + l (t=code tile, l=lane): 16B at c*16 =
//                   { fp8(1024*e[16t+(l&15)][(l>>4)*8 .. +8)),
//                     fp8(1024*e[16t+(l&15)][32+(l>>4)*8 .. +8)) }
//  [65536, 69632)   e2 fp32[1024] (unscaled, exact)
#define WS_E2   65536

// LDS: mirrors ws [0,69632) linearly, + idx + loss scratch
#define SM_E2   65536
#define SM_IDX  69632   // 8 waves * 32 int = 1024B
#define SM_LOSS 70656   // 8 floats
#define SM_SZ   70688

__device__ __forceinline__ uint32_t pk4(float a, float b, float c, float d) {
  int v = 0;
  v = __builtin_amdgcn_cvt_pk_fp8_f32(a, b, v, false);
  v = __builtin_amdgcn_cvt_pk_fp8_f32(c, d, v, true);
  return (uint32_t)v;
}

__device__ __forceinline__ float d4(f32x4 v) {
  return v[0]*v[0] + v[1]*v[1] + v[2]*v[2] + v[3]*v[3];
}

// 8 blocks x 512: thread -> one 16B fp8 chunk + one e2 quarter-row (coalesced).
// Also zeroes the loss slot (replaces a memset dispatch).
__global__ __launch_bounds__(512) void prep_kernel(const float* __restrict__ cb,
                                                   uint8_t* __restrict__ ws,
                                                   float* __restrict__ loss) {
  const int tid = threadIdx.x;
  if (blockIdx.x == 0 && tid == 0) *loss = 0.f;
  const int c = blockIdx.x * 512 + tid;          // 0..4095
  const int t = c >> 6, l = c & 63, lr = l & 15, lg = l >> 4;
  {
    const float* row = cb + (size_t)(t * 16 + lr) * 64 + lg * 8;
    f32x4 a0 = *(const f32x4*)row;
    f32x4 a1 = *(const f32x4*)(row + 4);
    f32x4 b0 = *(const f32x4*)(row + 32);
    f32x4 b1 = *(const f32x4*)(row + 36);
    u32x4 o;
    o[0] = pk4(1024.f*a0[0], 1024.f*a0[1], 1024.f*a0[2], 1024.f*a0[3]);
    o[1] = pk4(1024.f*a1[0], 1024.f*a1[1], 1024.f*a1[2], 1024.f*a1[3]);
    o[2] = pk4(1024.f*b0[0], 1024.f*b0[1], 1024.f*b0[2], 1024.f*b0[3]);
    o[3] = pk4(1024.f*b1[0], 1024.f*b1[1], 1024.f*b1[2], 1024.f*b1[3]);
    *(u32x4*)(ws + (size_t)c * 16) = o;
  }
  {
    const int r = blockIdx.x * 128 + (tid >> 2), q = tid & 3;
    const float* rp = cb + (size_t)r * 64 + q * 16;
    f32x4 v0 = *(const f32x4*)rp;
    f32x4 v1 = *(const f32x4*)(rp + 4);
    f32x4 v2 = *(const f32x4*)(rp + 8);
    f32x4 v3 = *(const f32x4*)(rp + 12);
    float s = d4(v0) + d4(v1) + d4(v2) + d4(v3);
    s += __shfl_xor(s, 1, 64);
    s += __shfl_xor(s, 2, 64);
    if (q == 0) *(float*)(ws + WS_E2 + (size_t)r * 4) = s;
  }
}

// R2 core: 512 blocks x 512 threads, 32 rows/wave, ONE scan/wave, 16 waves/CU.
__global__ __launch_bounds__(512, 4) void vq_main(const float* __restrict__ x,
                                                  const float* __restrict__ cb,
                                                  float* __restrict__ out,
                                                  const uint8_t* __restrict__ ws,
                                                  float* __restrict__ loss) {
  __shared__ __align__(16) uint8_t smem[SM_SZ];
  const int tid = threadIdx.x, lane = tid & 63, w = tid >> 6;
  const int lr = lane & 15, lg = lane >> 4;
  const int rowbase = blockIdx.x * 256 + w * 32;

  // ---- issue async staging first: fp8 codebook (64KB) + e2 (4KB) ----
  {
    const uint8_t* gsrc = ws + (size_t)w * 8192 + (size_t)lane * 16;
    uint8_t* ldst = smem + w * 8192;
#pragma unroll
    for (int i = 0; i < 8; ++i)
      __builtin_amdgcn_global_load_lds(
          (const __attribute__((address_space(1))) uint32_t*)(gsrc + i * 1024),
          (__attribute__((address_space(3))) uint32_t*)(ldst + i * 1024), 16, 0, 0);
    if (w < 4)
      __builtin_amdgcn_global_load_lds(
          (const __attribute__((address_space(1))) uint32_t*)(ws + WS_E2 + (size_t)w * 1024 + (size_t)lane * 16),
          (__attribute__((address_space(3))) uint32_t*)(smem + SM_E2 + w * 1024), 16, 0, 0);
  }

  // ---- load x rows (nontemporal), fp32 x^2 partial, pack fp8 A-frags ----
  float x2p = 0.f;
  long afrag[2][2];
#pragma unroll
  for (int rt = 0; rt < 2; ++rt) {
    const float* rp = x + (size_t)(rowbase + rt * 16 + lr) * 64 + lg * 8;
    f32x4 a0 = __builtin_nontemporal_load((const f32x4*)rp);
    f32x4 a1 = __builtin_nontemporal_load((const f32x4*)(rp + 4));
    f32x4 b0 = __builtin_nontemporal_load((const f32x4*)(rp + 32));
    f32x4 b1 = __builtin_nontemporal_load((const f32x4*)(rp + 36));
    x2p += d4(a0) + d4(a1) + d4(b0) + d4(b1);
    uint32_t w0 = pk4(a0[0], a0[1], a0[2], a0[3]);
    uint32_t w1 = pk4(a1[0], a1[1], a1[2], a1[3]);
    uint32_t w2 = pk4(b0[0], b0[1], b0[2], b0[3]);
    uint32_t w3 = pk4(b1[0], b1[1], b1[2], b1[3]);
    afrag[rt][0] = (long)(((uint64_t)w1 << 32) | w0);
    afrag[rt][1] = (long)(((uint64_t)w3 << 32) | w2);
  }
  __syncthreads();

  // ---- single scan: 32 tile-PAIRS, keys via max3 ----
  float kmax[2][4];
#pragma unroll
  for (int rt = 0; rt < 2; ++rt)
#pragma unroll
    for (int r = 0; r < 4; ++r) kmax[rt][r] = __builtin_bit_cast(float, 0xFF800000u);

  const uint8_t* bptr = smem + lane * 16;
  uint32_t jv = (uint32_t)lr;
#pragma unroll 2
  for (int tp = 0; tp < 32; ++tp) {
    u32x4 bA = *(const u32x4*)(bptr + (size_t)(2 * tp) * 1024);
    u32x4 bB = *(const u32x4*)(bptr + (size_t)(2 * tp + 1) * 1024);
    long bA0 = (long)(((uint64_t)bA[1] << 32) | bA[0]);
    long bA1 = (long)(((uint64_t)bA[3] << 32) | bA[2]);
    long bB0 = (long)(((uint64_t)bB[1] << 32) | bB[0]);
    long bB1 = (long)(((uint64_t)bB[3] << 32) | bB[2]);
    uint32_t jvB = jv | 16u;
#pragma unroll
    for (int rt = 0; rt < 2; ++rt) {
      f32x4 accA = {0.f, 0.f, 0.f, 0.f}, accB = {0.f, 0.f, 0.f, 0.f};
      accA = __builtin_amdgcn_mfma_f32_16x16x32_fp8_fp8(afrag[rt][0], bA0, accA, 0, 0, 0);
      accA = __builtin_amdgcn_mfma_f32_16x16x32_fp8_fp8(afrag[rt][1], bA1, accA, 0, 0, 0);
      accB = __builtin_amdgcn_mfma_f32_16x16x32_fp8_fp8(afrag[rt][0], bB0, accB, 0, 0, 0);
      accB = __builtin_amdgcn_mfma_f32_16x16x32_fp8_fp8(afrag[rt][1], bB1, accB, 0, 0, 0);
#pragma unroll
      for (int r = 0; r < 4; ++r) {
        uint32_t kA = (__builtin_bit_cast(uint32_t, accA[r]) & 0xFFFFFC00u) | jv;
        uint32_t kB = (__builtin_bit_cast(uint32_t, accB[r]) & 0xFFFFFC00u) | jvB;
        kmax[rt][r] = fmaxf(fmaxf(kmax[rt][r], __builtin_bit_cast(float, kA)),
                            __builtin_bit_cast(float, kB));
      }
    }
    jv += 32;
  }

  // ---- reduce over the 16 code-slot lanes; loss dot term ----
  float lsum = x2p;
#pragma unroll
  for (int rt = 0; rt < 2; ++rt)
#pragma unroll
    for (int r = 0; r < 4; ++r) {
      float v = kmax[rt][r];
#pragma unroll
      for (int m = 1; m < 16; m <<= 1) v = fmaxf(v, __shfl_xor(v, m, 64));
      kmax[rt][r] = v;
      // acc = 1024*(x.e); -2*dot per row, replicated over 16 lanes -> /8192
      lsum -= __builtin_bit_cast(float, __builtin_bit_cast(uint32_t, v) & 0xFFFFFC00u)
              * (1.0f / 8192.0f);
    }

  // ---- idx exchange (wave-local) ----
  int* sh_idx = (int*)(smem + SM_IDX) + w * 32;
  if (lr == 0) {
#pragma unroll
    for (int rt = 0; rt < 2; ++rt)
#pragma unroll
      for (int r = 0; r < 4; ++r)
        sh_idx[rt * 16 + lg * 4 + r] =
            (int)(__builtin_bit_cast(uint32_t, kmax[rt][r]) & 1023u);
  }
  asm volatile("s_waitcnt lgkmcnt(0)" ::: "memory");

  // ---- gather fp32 codebook rows (L2) + store + e2 loss term ----
  const float* e2f = (const float*)(smem + SM_E2);
#pragma unroll
  for (int it = 0; it < 8; ++it) {
    int rloc = it * 4 + lg;
    int idx = sh_idx[rloc];
    f32x4 q = *(const f32x4*)(cb + (size_t)idx * 64 + lr * 4);
    __builtin_nontemporal_store(q, (f32x4*)(out + (size_t)(rowbase + rloc) * 64 + lr * 4));
    if (lr == 0) lsum += e2f[idx];
  }

  // ---- loss: wave -> block -> global atomic (zeroed by prep) ----
#pragma unroll
  for (int m = 1; m < 64; m <<= 1) lsum += __shfl_xor(lsum, m, 64);
  float* shl = (float*)(smem + SM_LOSS);
  if (lane == 0) shl[w] = lsum;
  __syncthreads();
  if (tid == 0) {
    float s = 0.f;
#pragma unroll
    for (int i = 0; i < 8; ++i) s += shl[i];
    atomicAdd(loss, s * (1.25f / 8388608.0f));
  }
}

extern "C" void kernel_launch(void* const* d_in, const int* in_sizes, int n_in,
                              void* d_out, int out_size, void* d_ws, size_t ws_size,
                              hipStream_t stream) {
  const float* x  = (const float*)d_in[0];
  const float* cb = (const float*)d_in[1];
  float* out = (float*)d_out;
  uint8_t* ws = (uint8_t*)d_ws;
  float* loss = out + 8388608;

  hipLaunchKernelGGL(prep_kernel, dim3(8), dim3(512), 0, stream, cb, ws, loss);
  hipLaunchKernelGGL(vq_main, dim3(512), dim3(512), 0, stream, x, cb, out, ws, loss);
}